// Round 10
// baseline (132.208 us; speedup 1.0000x reference)
//
#include <hip/hip_runtime.h>
#include <math.h>

#define DIMC 512
#define NG 8
// q pre-scale: 64^-0.5 * log2(e)  (so scores come out in exp2 units)
#define QSCALE 0.18033688011112042f
// softmax fixed shift: 5 * log2(e)
#define MSHIFT 7.2134752044448170f

typedef _Float16 half8 __attribute__((ext_vector_type(8)));
typedef __fp16 fp16x2 __attribute__((ext_vector_type(2)));
typedef float f32x4 __attribute__((ext_vector_type(4)));

// build a half8 MFMA fragment from 8 consecutive global f32
__device__ __forceinline__ half8 frag_f32(const float* p) {
    float4 a = *(const float4*)p;
    float4 b = *(const float4*)(p + 4);
    union { fp16x2 h2[4]; half8 h8; } u;
    u.h2[0] = __builtin_amdgcn_cvt_pkrtz(a.x, a.y);
    u.h2[1] = __builtin_amdgcn_cvt_pkrtz(a.z, a.w);
    u.h2[2] = __builtin_amdgcn_cvt_pkrtz(b.x, b.y);
    u.h2[3] = __builtin_amdgcn_cvt_pkrtz(b.z, b.w);
    return u.h8;
}

// ---------------- fused front-end v2: de-scattered ----------------
// 64 q-positions / 16 m-positions per block -> 512 blocks -> 2 blocks/CU.
// Staging dense/coalesced (f32->f16, stride-136 rows); frags via ds_read_b128;
// halo folded into a 2-row zero-padded MFMA on wave 0.
// Also: first 128 blocks cast Wo f32->f16 in K-PANEL layout [c/8][d][8]
// (consumed 2 dispatches later by k_out as coalesced B-frags).
__global__ __launch_bounds__(256, 2) void k_front(
    const float* __restrict__ x, const float* __restrict__ px,
    const float* __restrict__ Wq, const float* __restrict__ Wk,
    const float* __restrict__ Wv, const float* __restrict__ Wo,
    const float* __restrict__ Wdw, const float* __restrict__ bdw,
    const float* __restrict__ Wp, _Float16* __restrict__ qh,
    _Float16* __restrict__ kt16, _Float16* __restrict__ vt16,
    _Float16* __restrict__ Woh, int n, int m)
{
    __shared__ float Os[64*69];        // [i][oc] q tile, stride 69
    __shared__ float hl[2][64];        // halo q: [side][c]
    __shared__ float part[16][16];
    __shared__ int   x0s[16];
    __shared__ float w1s[16];
    __shared__ _Float16 kvs[2][16*72]; // gathered kv, per stream
    __shared__ _Float16 SRCs[64*136];  // staged SRC slice [i][c], f16
    __shared__ _Float16 Wqs[64*136];   // staged Wq slice [oc][c], f16
    int g  = blockIdx.x & 7;
    int jt = blockIdx.x >> 3;
    int P0 = jt*64, j0 = jt*16;
    int t  = threadIdx.x;
    int lane = t & 63, w = t >> 6;
    int l15 = lane & 15, quad = lane >> 4;
    const float* SRC = (g < 4) ? px : x;    // concat puts prev first
    int cbase = (g & 3) * 128;

    // Wo cast -> PANEL layout Woh[(c>>3)][d][8] (first 128 blocks, 2048 elems each)
    if (blockIdx.x < 128) {
        int idx = blockIdx.x*2048 + t*8;
        int d = idx >> 9, c0 = idx & 511;       // 8 consecutive c in one panel
        float4 a = *(const float4*)&Wo[idx];
        float4 b = *(const float4*)&Wo[idx+4];
        union { fp16x2 h2[4]; uint4 v; } pk;
        pk.h2[0] = __builtin_amdgcn_cvt_pkrtz(a.x, a.y);
        pk.h2[1] = __builtin_amdgcn_cvt_pkrtz(a.z, a.w);
        pk.h2[2] = __builtin_amdgcn_cvt_pkrtz(b.x, b.y);
        pk.h2[3] = __builtin_amdgcn_cvt_pkrtz(b.z, b.w);
        *(uint4*)&Woh[(c0>>3)*4096 + d*8] = pk.v;
    }

    // ---- stage SRC + Wq slices into LDS (dense coalesced, f32->f16) ----
    {
        int r = t >> 2, c0 = (t & 3) * 32;
        const float* sp = &SRC[(size_t)(P0 + r)*DIMC + cbase + c0];
        const float* wp = &Wq[(size_t)(g*64 + r)*128 + c0];
#pragma unroll
        for (int u = 0; u < 4; ++u) {
            *(half8*)&SRCs[r*136 + c0 + u*8] = frag_f32(sp + u*8);
            *(half8*)&Wqs [r*136 + c0 + u*8] = frag_f32(wp + u*8);
        }
    }

    // halo A-frags (wave 0): rows P0-1 (l15==0) and P0+64 (l15==1), zero-padded
    half8 afh[4];
    if (w == 0) {
        int p = (l15 == 0) ? (P0 - 1) : (P0 + 64);
        bool hv = (l15 < 2) && (p >= 0) && (p < n);
        half8 z;
#pragma unroll
        for (int u = 0; u < 8; ++u) z[u] = (_Float16)0.f;
#pragma unroll
        for (int ks = 0; ks < 4; ++ks)
            afh[ks] = hv ? frag_f32(&SRC[(size_t)p*DIMC + cbase + ks*32 + quad*8]) : z;
    }
    __syncthreads();

    // main q tile via f16 MFMA: wave w owns i-strip [P0+w*16, +16); frags from LDS
    half8 af[4];
#pragma unroll
    for (int ks = 0; ks < 4; ++ks)
        af[ks] = *(const half8*)&SRCs[(w*16 + l15)*136 + ks*32 + quad*8];
    f32x4 acc[4], acch[4];
#pragma unroll
    for (int nt = 0; nt < 4; ++nt) { acc[nt] = (f32x4){0.f,0.f,0.f,0.f}; acch[nt] = (f32x4){0.f,0.f,0.f,0.f}; }
#pragma unroll
    for (int ks = 0; ks < 4; ++ks)
#pragma unroll
        for (int nt = 0; nt < 4; ++nt) {
            half8 bf = *(const half8*)&Wqs[(nt*16 + l15)*136 + ks*32 + quad*8];
            acc[nt] = __builtin_amdgcn_mfma_f32_16x16x32_f16(af[ks], bf, acc[nt], 0, 0, 0);
            if (w == 0)
                acch[nt] = __builtin_amdgcn_mfma_f32_16x16x32_f16(afh[ks], bf, acch[nt], 0, 0, 0);
        }
    // C-layout -> Os[i][oc]; halo rows 0,1 of acch -> hl[side][oc]
#pragma unroll
    for (int nt = 0; nt < 4; ++nt)
#pragma unroll
        for (int r = 0; r < 4; ++r)
            Os[(w*16 + quad*4 + r)*69 + nt*16 + l15] = acc[nt][r];
    if (w == 0 && quad == 0)
#pragma unroll
        for (int nt = 0; nt < 4; ++nt) {
            hl[0][nt*16 + l15] = acch[nt][0];
            hl[1][nt*16 + l15] = acch[nt][1];
        }
    __syncthreads();

    // qh f16 [h][i][d] with QSCALE: thread covers a quarter row (16 f16)
    {
        int i = t >> 2, hf = t & 3;
        union { _Float16 h[16]; uint4 v[2]; } pk;
#pragma unroll
        for (int u = 0; u < 16; ++u) pk.h[u] = (_Float16)(Os[i*69 + hf*16 + u] * QSCALE);
        uint4* dst = (uint4*)&qh[((size_t)g*n + P0 + i)*64 + hf*16];
        dst[0] = pk.v[0]; dst[1] = pk.v[1];
    }

    // offset net straight from LDS: thread = (j = t&15, cg = t>>4, 4 channels each)
    {
        int j = t & 15, cg = t >> 4;
        float acco = 0.f;
#pragma unroll
        for (int cc = 0; cc < 4; ++cc) {
            int c = cg*4 + cc;
            float h = bdw[c];
#pragma unroll
            for (int tt = 0; tt < 6; ++tt) {
                int lp = 4*j + tt - 1;
                float val = (lp < 0) ? hl[0][c] : (lp >= 64 ? hl[1][c] : Os[lp*69 + c]);
                h += Wdw[c*6 + tt] * val;
            }
            float ge = 0.5f * h * (1.0f + erff(h * 0.70710678118654752f));  // exact gelu
            acco += Wp[c] * ge;
        }
        part[cg][j] = acco;
    }
    __syncthreads();
    if (t < 16) {
        float off = 0.f;
#pragma unroll
        for (int cg2 = 0; cg2 < 16; ++cg2) off += part[cg2][t];
        off = tanhf(off) * 4.0f;
        int jg = j0 + t;
        float vg  = 2.0f * ((float)jg + off) / (float)(m - 1) - 1.0f;
        float pos = ((vg + 1.0f) * (float)n - 1.0f) * 0.5f;
        float x0  = floorf(pos);
        x0s[t] = (int)x0;
        w1s[t] = pos - x0;
    }
    __syncthreads();

    // grid-sample gather, both streams (prefetch loads, then lerp+commit)
    {
        float a0[4], a1[4], b0[4], b1[4], wg[4];
#pragma unroll
        for (int jj = 0; jj < 4; ++jj) {
            int j = jj*4 + w;
            int ii = x0s[j];
            wg[jj] = w1s[j];
            bool v0 = (ii   >= 0 && ii   < n);
            bool v1 = (ii+1 >= 0 && ii+1 < n);
            a0[jj] = v0 ? px[(size_t)ii*DIMC + g*64 + lane]     : 0.f;
            a1[jj] = v1 ? px[(size_t)(ii+1)*DIMC + g*64 + lane] : 0.f;
            b0[jj] = v0 ? x[(size_t)ii*DIMC + g*64 + lane]      : 0.f;
            b1[jj] = v1 ? x[(size_t)(ii+1)*DIMC + g*64 + lane]  : 0.f;
        }
#pragma unroll
        for (int jj = 0; jj < 4; ++jj) {
            kvs[0][(jj*4 + w)*72 + lane] = (_Float16)(a0[jj]*(1.0f - wg[jj]) + a1[jj]*wg[jj]);
            kvs[1][(jj*4 + w)*72 + lane] = (_Float16)(b0[jj]*(1.0f - wg[jj]) + b1[jj]*wg[jj]);
        }
    }
    __syncthreads();

    // k/v convs: B-frags from global (shared across streams); wave w owns oc-strip w*16
    half8 bk[2], bv[2];
#pragma unroll
    for (int ks = 0; ks < 2; ++ks) {
        bk[ks] = frag_f32(&Wk[(size_t)(g*64 + w*16 + l15)*64 + ks*32 + quad*8]);
        bv[ks] = frag_f32(&Wv[(size_t)(g*64 + w*16 + l15)*64 + ks*32 + quad*8]);
    }
#pragma unroll
    for (int s = 0; s < 2; ++s) {
        half8 afk[2];
#pragma unroll
        for (int ks = 0; ks < 2; ++ks)
            afk[ks] = *(const half8*)&kvs[s][l15*72 + ks*32 + quad*8];
        f32x4 ack = (f32x4){0.f,0.f,0.f,0.f};
        f32x4 acv = (f32x4){0.f,0.f,0.f,0.f};
#pragma unroll
        for (int ks = 0; ks < 2; ++ks) {
            ack = __builtin_amdgcn_mfma_f32_16x16x32_f16(afk[ks], bk[ks], ack, 0, 0, 0);
            acv = __builtin_amdgcn_mfma_f32_16x16x32_f16(afk[ks], bv[ks], acv, 0, 0, 0);
        }
        size_t hb = (size_t)(s*8 + g);
#pragma unroll
        for (int r = 0; r < 4; ++r)
            kt16[(hb*m + j0 + quad*4 + r)*64 + w*16 + l15] = (_Float16)ack[r];
        union { fp16x2 h2[2]; uint2 v; } pv;
        pv.h2[0] = __builtin_amdgcn_cvt_pkrtz(acv[0], acv[1]);
        pv.h2[1] = __builtin_amdgcn_cvt_pkrtz(acv[2], acv[3]);
        *(uint2*)&vt16[(hb*64 + w*16 + l15)*m + j0 + quad*4] = pv.v;   // 4 consecutive j
    }
}

// ---------------- flash attention v9: 512 threads / 128 q-rows -> 2 blocks/CU, 16 waves/CU ----------------
// Recombines v7 (2 blocks/CU: barriers overlap across blocks) with v8 (8 waves share
// one K/V staging: 1 load + 1 commit per thread per array). Each wave owns a 16-row
// i-strip; per-wave state halves (VGPR ~75 < 128 cap for 4 waves/SIMD). LDS 55 KB.
__global__ __launch_bounds__(512, 2) void k_attn(
    const _Float16* __restrict__ qh, const _Float16* __restrict__ kt16,
    const _Float16* __restrict__ vt16, _Float16* __restrict__ aoh, int n, int m)
{
    __shared__ _Float16 Ks[2][64*72]; // K tile [j][d], row stride 72
    __shared__ _Float16 Vs[2][64*72]; // V tile [d][j], row stride 72
    __shared__ _Float16 Ps[128*72];   // P^T strips; reused as O transpose buffer in epilogue
    int nit = n >> 7;                 // 128 q-rows per block
    int it = blockIdx.x % nit;
    int h  = (blockIdx.x / nit) & 7;
    int s  = blockIdx.x / (nit*8);
    int t  = threadIdx.x;
    int lane = t & 63, w = t >> 6;    // w in 0..7
    int l15 = lane & 15, quad = lane >> 4;
    int i0 = it*128;

    // Q B-frags: wave w owns i-strip [i0 + w*16, +16)
    const _Float16* qb = &qh[((size_t)h*n + i0)*64];
    half8 bqv[2];
#pragma unroll
    for (int ks = 0; ks < 2; ++ks)
        bqv[ks] = *(const half8*)&qb[(w*16 + l15)*64 + ks*32 + quad*8];

    const _Float16* kb = &kt16[(size_t)(s*8+h)*m*64];   // [j][d]
    const _Float16* vb = &vt16[(size_t)(s*8+h)*64*m];   // [d][j]

    int r0 = t >> 3, oct = t & 7;     // one row per thread (512 threads, 64 rows x 8 chunks)

    float lsum = 0.f;
    f32x4 oaccT[4];
#pragma unroll
    for (int dt = 0; dt < 4; ++dt) oaccT[dt] = (f32x4){0.f,0.f,0.f,0.f};

    // prefetch + commit K/V tile 0 into buf 0 (coalesced; one row per thread)
    uint4 pv0 = *(const uint4*)&vb[(size_t)r0*m + oct*8];
    uint4 pk0 = *(const uint4*)&kb[(size_t)r0*64 + oct*8];
    *(uint4*)&Vs[0][r0*72 + oct*8] = pv0;
    *(uint4*)&Ks[0][r0*72 + oct*8] = pk0;

    int ntile = m >> 6;
    for (int tk = 0; tk < ntile; ++tk) {
        bool pf = (tk + 1 < ntile);
        if (pf) {   // next K/V tiles' global loads, latency hidden by compute
            pv0 = *(const uint4*)&vb[(size_t)r0*m + (tk+1)*64 + oct*8];
            pk0 = *(const uint4*)&kb[(size_t)((tk+1)*64 + r0)*64 + oct*8];
        }

        __syncthreads();   // K/V buf[tk&1] committed; prior tile's reads done
        const _Float16* KB = Ks[tk & 1];
        const _Float16* VB = Vs[tk & 1];
        half8 aqv[2][4];
#pragma unroll
        for (int ks = 0; ks < 2; ++ks)
#pragma unroll
            for (int jt = 0; jt < 4; ++jt)
                aqv[ks][jt] = *(const half8*)&KB[(jt*16 + l15)*72 + ks*32 + quad*8];
        half8 avv[2][4];
#pragma unroll
        for (int ks = 0; ks < 2; ++ks)
#pragma unroll
            for (int dt = 0; dt < 4; ++dt)
                avv[ks][dt] = *(const half8*)&VB[(dt*16 + l15)*72 + ks*32 + quad*8];

        // --- S^T = K Q^T over wave's 16-i strip ---
        f32x4 accs[4];
#pragma unroll
        for (int jt = 0; jt < 4; ++jt) accs[jt] = (f32x4){0.f,0.f,0.f,0.f};
        __builtin_amdgcn_s_setprio(1);
#pragma unroll
        for (int ks = 0; ks < 2; ++ks)
#pragma unroll
            for (int jt = 0; jt < 4; ++jt)
                accs[jt] = __builtin_amdgcn_mfma_f32_16x16x32_f16(
                    aqv[ks][jt], bqv[ks], accs[jt], 0, 0, 0);
        __builtin_amdgcn_s_setprio(0);

        // --- p = exp2(t - MSHIFT); partial row sums; pack + vectored P^T write (wave-private) ---
#pragma unroll
        for (int jt = 0; jt < 4; ++jt) {
            f32x4 p;
#pragma unroll
            for (int r = 0; r < 4; ++r) p[r] = __builtin_amdgcn_exp2f(accs[jt][r] - MSHIFT);
            lsum += (p[0]+p[1]) + (p[2]+p[3]);
            union { fp16x2 h; int i; } c0, c1;
            c0.h = __builtin_amdgcn_cvt_pkrtz(p[0], p[1]);
            c1.h = __builtin_amdgcn_cvt_pkrtz(p[2], p[3]);
            *(int2*)&Ps[(w*16 + l15)*72 + jt*16 + quad*4] = make_int2(c0.i, c1.i);
        }

        // --- O^T += V^T P^T ---
        __builtin_amdgcn_s_setprio(1);
#pragma unroll
        for (int ks = 0; ks < 2; ++ks) {
            half8 bp = *(const half8*)&Ps[(w*16 + l15)*72 + ks*32 + quad*8];
#pragma unroll
            for (int dt = 0; dt < 4; ++dt)
                oaccT[dt] = __builtin_amdgcn_mfma_f32_16x16x32_f16(
                    avv[ks][dt], bp, oaccT[dt], 0, 0, 0);
        }
        __builtin_amdgcn_s_setprio(0);

        if (pf) {   // commit next K/V tiles into the other buffer
            int b2 = (tk + 1) & 1;
            *(uint4*)&Vs[b2][r0*72 + oct*8] = pv0;
            *(uint4*)&Ks[b2][r0*72 + oct*8] = pk0;
        }
    }

    // --- finalize ---
    lsum += __shfl_xor(lsum, 16, 64);
    lsum += __shfl_xor(lsum, 32, 64);
    float inv = 1.0f / lsum;
#pragma unroll
    for (int dt = 0; dt < 4; ++dt)
#pragma unroll
        for (int r = 0; r < 4; ++r)
            Ps[(w*16 + l15)*72 + dt*16 + quad*4 + r] = (_Float16)(oaccT[dt][r] * inv);
    {
        int row = w*16 + (lane >> 2);                // 0..127
        int dbase = (lane & 3) * 16;                 // 16 f16 per thread
        int pbase = s*64 + h*8 + (dbase >> 3);       // panel index of c' = s*512+h*64+dbase
        size_t APs = (size_t)n * 8;                  // f16 per panel
#pragma unroll
        for (int k2 = 0; k2 < 2; ++k2) {
            uint4 v = *(uint4*)&Ps[row*72 + dbase + k2*8];
            *(uint4*)&aoh[(size_t)(pbase + k2)*APs + (size_t)(i0 + row)*8] = v;
        }
    }
}

// ---------------- Wo GEMM, f16 MFMA, zero-LDS, PANEL-layout operands ----------------
// aoh and Woh are stored as [K-panel][row][8] -> every A/B fragment load is 16 lanes
// x contiguous 16B (2 cache lines) instead of a 16-line scatter. Linearity fold:
// out = bias + 0.5*(O_s0 + O_s1)·Wo — panels p and p+64 share the same Wo panel.
__global__ __launch_bounds__(256) void k_out(
    const _Float16* __restrict__ aoh, const _Float16* __restrict__ Woh,
    const float* __restrict__ bo, float* __restrict__ out, int n)
{
    int i0 = blockIdx.x*64, d0 = blockIdx.y*64;
    int t = threadIdx.x;
    int lane = t & 63, w = t >> 6;
    int l15 = lane & 15, quad = lane >> 4;
    f32x4 oacc[4];
#pragma unroll
    for (int dt = 0; dt < 4; ++dt) oacc[dt] = (f32x4){0.f,0.f,0.f,0.f};

    size_t APs = (size_t)n * 8;
    int arow = (i0 + w*16 + l15) * 8;
#pragma unroll 4
    for (int ks = 0; ks < 16; ++ks) {            // K' = 1024 folded to 512 via stream pre-sum
        int p = ks*4 + quad;                     // A/B panel for this (ks, quad)
        half8 aq0 = *(const half8*)&aoh[(size_t)p*APs + arow];
        half8 aq1 = *(const half8*)&aoh[(size_t)(p + 64)*APs + arow];
        half8 aqs = aq0 + aq1;                   // packed f16 add; 0.5 applied at epilogue
#pragma unroll
        for (int dt = 0; dt < 4; ++dt) {
            half8 bw = *(const half8*)&Woh[(size_t)p*4096 + (d0 + dt*16 + l15)*8];
            oacc[dt] = __builtin_amdgcn_mfma_f32_16x16x32_f16(aqs, bw, oacc[dt], 0, 0, 0);
        }
    }
#pragma unroll
    for (int dt = 0; dt < 4; ++dt) {
        float bias = bo[d0 + dt*16 + l15];
#pragma unroll
        for (int r = 0; r < 4; ++r)
            out[(size_t)(i0 + w*16 + quad*4 + r)*DIMC + d0 + dt*16 + l15]
                = bias + 0.5f*oacc[dt][r];
    }
}

extern "C" void kernel_launch(void* const* d_in, const int* in_sizes, int n_in,
                              void* d_out, int out_size, void* d_ws, size_t ws_size,
                              hipStream_t stream)
{
    const float* x   = (const float*)d_in[0];
    const float* px  = (const float*)d_in[1];
    const float* Wq  = (const float*)d_in[2];
    const float* Wk  = (const float*)d_in[3];
    const float* Wv  = (const float*)d_in[4];
    const float* Wo  = (const float*)d_in[5];
    const float* bo  = (const float*)d_in[6];
    const float* Wdw = (const float*)d_in[7];
    const float* bdw = (const float*)d_in[8];
    const float* Wp  = (const float*)d_in[9];
    float* out = (float*)d_out;
    int n = in_sizes[0] / DIMC;     // 4096
    int m = n / 4;                  // 1024

    _Float16* qhf  = (_Float16*)d_ws;                 // 8*n*64 f16   [h][i][d]
    _Float16* kt16 = qhf + (size_t)8*n*64;            // 2*8*m*64 f16 [s][h][j][d]
    _Float16* vt16 = kt16 + (size_t)16*m*64;          // 2*8*m*64 f16 [s][h][d][j]
    _Float16* aoh  = vt16 + (size_t)16*m*64;          // n*1024 f16   PANEL [c'/8][i][8]
    _Float16* Woh  = aoh + (size_t)n*1024;            // 512*512 f16  PANEL [c/8][d][8]

    k_front<<<8*(m/16),    256, 0, stream>>>(x, px, Wq, Wk, Wv, Wo, Wdw, bdw, Wp,
                                             qhf, kt16, vt16, Woh, n, m);
    k_attn <<<2*8*(n/128), 512, 0, stream>>>(qhf, kt16, vt16, aoh, n, m);
    k_out  <<<dim3(n/64, 8), 256, 0, stream>>>(aoh, Woh, bo, out, n);
}

// Round 11
// 128.510 us; speedup vs baseline: 1.0288x; 1.0288x over previous
//
#include <hip/hip_runtime.h>
#include <math.h>

#define DIMC 512
#define NG 8
// q pre-scale: 64^-0.5 * log2(e)  (so scores come out in exp2 units)
#define QSCALE 0.18033688011112042f
// softmax fixed shift: 5 * log2(e)
#define MSHIFT 7.2134752044448170f

typedef _Float16 half8 __attribute__((ext_vector_type(8)));
typedef __fp16 fp16x2 __attribute__((ext_vector_type(2)));
typedef float f32x4 __attribute__((ext_vector_type(4)));

// build a half8 MFMA fragment from 8 consecutive global f32
__device__ __forceinline__ half8 frag_f32(const float* p) {
    float4 a = *(const float4*)p;
    float4 b = *(const float4*)(p + 4);
    union { fp16x2 h2[4]; half8 h8; } u;
    u.h2[0] = __builtin_amdgcn_cvt_pkrtz(a.x, a.y);
    u.h2[1] = __builtin_amdgcn_cvt_pkrtz(a.z, a.w);
    u.h2[2] = __builtin_amdgcn_cvt_pkrtz(b.x, b.y);
    u.h2[3] = __builtin_amdgcn_cvt_pkrtz(b.z, b.w);
    return u.h8;
}

// ---------------- fused front-end v3: 512 threads / 128 q-rows / 32 m-positions ----------------
// v8-analog scaling (keep 16 rows/wave for q-MFMA, grow the block): 256 blocks,
// 1 block/CU, 8 waves/CU (same wave count as v2's 2x256). Per-block fixed costs
// (Wq staging, halo, offset reduce, barriers) halve per row. LDS ~100 KB.
// kv-conv waves split (stream, oc-strip) = (w>>2, w&3). All loads keep the
// proven dense/coalesced patterns; frags via ds_read_b128.
__global__ __launch_bounds__(512, 1) void k_front(
    const float* __restrict__ x, const float* __restrict__ px,
    const float* __restrict__ Wq, const float* __restrict__ Wk,
    const float* __restrict__ Wv, const float* __restrict__ Wo,
    const float* __restrict__ Wdw, const float* __restrict__ bdw,
    const float* __restrict__ Wp, _Float16* __restrict__ qh,
    _Float16* __restrict__ kt16, _Float16* __restrict__ vt16,
    _Float16* __restrict__ Woh, int n, int m)
{
    __shared__ float Os[128*69];       // [i][oc] q tile, stride 69
    __shared__ float hl[2][64];        // halo q: [side][c]
    __shared__ float part[16][32];
    __shared__ int   x0s[32];
    __shared__ float w1s[32];
    __shared__ _Float16 kvs[2][32*72]; // gathered kv, per stream
    __shared__ _Float16 SRCs[128*136]; // staged SRC slice [i][c], f16
    __shared__ _Float16 Wqs[64*136];   // staged Wq slice [oc][c], f16
    int g  = blockIdx.x & 7;
    int jt = blockIdx.x >> 3;
    int P0 = jt*128, j0 = jt*32;
    int t  = threadIdx.x;
    int lane = t & 63, w = t >> 6;     // w in 0..7
    int l15 = lane & 15, quad = lane >> 4;
    const float* SRC = (g < 4) ? px : x;    // concat puts prev first
    int cbase = (g & 3) * 128;

    // Wo cast -> PANEL layout Woh[(c>>3)][d][8] (first 128 blocks, 2048 elems each)
    if (blockIdx.x < 128 && t < 256) {
        int idx = blockIdx.x*2048 + t*8;
        int d = idx >> 9, c0 = idx & 511;       // 8 consecutive c in one panel
        float4 a = *(const float4*)&Wo[idx];
        float4 b = *(const float4*)&Wo[idx+4];
        union { fp16x2 h2[4]; uint4 v; } pk;
        pk.h2[0] = __builtin_amdgcn_cvt_pkrtz(a.x, a.y);
        pk.h2[1] = __builtin_amdgcn_cvt_pkrtz(a.z, a.w);
        pk.h2[2] = __builtin_amdgcn_cvt_pkrtz(b.x, b.y);
        pk.h2[3] = __builtin_amdgcn_cvt_pkrtz(b.z, b.w);
        *(uint4*)&Woh[(c0>>3)*4096 + d*8] = pk.v;
    }

    // ---- stage SRC (128 rows) + Wq (64 rows) into LDS (dense coalesced, f32->f16) ----
    {
        int r = t >> 2, c0 = (t & 3) * 32;       // SRC: 4 threads per 512B row
        const float* sp = &SRC[(size_t)(P0 + r)*DIMC + cbase + c0];
#pragma unroll
        for (int u = 0; u < 4; ++u)
            *(half8*)&SRCs[r*136 + c0 + u*8] = frag_f32(sp + u*8);
        int rw = t >> 3, cw = (t & 7) * 16;      // Wq: 8 threads per 512B row
        const float* wp = &Wq[(size_t)(g*64 + rw)*128 + cw];
#pragma unroll
        for (int u = 0; u < 2; ++u)
            *(half8*)&Wqs[rw*136 + cw + u*8] = frag_f32(wp + u*8);
    }

    // halo A-frags (wave 0): rows P0-1 (l15==0) and P0+128 (l15==1), zero-padded
    half8 afh[4];
    if (w == 0) {
        int p = (l15 == 0) ? (P0 - 1) : (P0 + 128);
        bool hv = (l15 < 2) && (p >= 0) && (p < n);
        half8 z;
#pragma unroll
        for (int u = 0; u < 8; ++u) z[u] = (_Float16)0.f;
#pragma unroll
        for (int ks = 0; ks < 4; ++ks)
            afh[ks] = hv ? frag_f32(&SRC[(size_t)p*DIMC + cbase + ks*32 + quad*8]) : z;
    }
    __syncthreads();

    // main q tile via f16 MFMA: wave w owns i-strip [P0+w*16, +16); frags from LDS
    half8 af[4];
#pragma unroll
    for (int ks = 0; ks < 4; ++ks)
        af[ks] = *(const half8*)&SRCs[(w*16 + l15)*136 + ks*32 + quad*8];
    f32x4 acc[4], acch[4];
#pragma unroll
    for (int nt = 0; nt < 4; ++nt) { acc[nt] = (f32x4){0.f,0.f,0.f,0.f}; acch[nt] = (f32x4){0.f,0.f,0.f,0.f}; }
#pragma unroll
    for (int ks = 0; ks < 4; ++ks)
#pragma unroll
        for (int nt = 0; nt < 4; ++nt) {
            half8 bf = *(const half8*)&Wqs[(nt*16 + l15)*136 + ks*32 + quad*8];
            acc[nt] = __builtin_amdgcn_mfma_f32_16x16x32_f16(af[ks], bf, acc[nt], 0, 0, 0);
            if (w == 0)
                acch[nt] = __builtin_amdgcn_mfma_f32_16x16x32_f16(afh[ks], bf, acch[nt], 0, 0, 0);
        }
    // C-layout -> Os[i][oc]; halo rows 0,1 of acch -> hl[side][oc]
#pragma unroll
    for (int nt = 0; nt < 4; ++nt)
#pragma unroll
        for (int r = 0; r < 4; ++r)
            Os[(w*16 + quad*4 + r)*69 + nt*16 + l15] = acc[nt][r];
    if (w == 0 && quad == 0)
#pragma unroll
        for (int nt = 0; nt < 4; ++nt) {
            hl[0][nt*16 + l15] = acch[nt][0];
            hl[1][nt*16 + l15] = acch[nt][1];
        }
    __syncthreads();

    // qh f16 [h][i][d] with QSCALE: thread covers a quarter row (16 f16), 128 rows
    {
        int i = t >> 2, hf = t & 3;
        union { _Float16 h[16]; uint4 v[2]; } pk;
#pragma unroll
        for (int u = 0; u < 16; ++u) pk.h[u] = (_Float16)(Os[i*69 + hf*16 + u] * QSCALE);
        uint4* dst = (uint4*)&qh[((size_t)g*n + P0 + i)*64 + hf*16];
        dst[0] = pk.v[0]; dst[1] = pk.v[1];
    }

    // offset net straight from LDS: thread = (j = t&31, cg = t>>5, 4 channels each)
    {
        int j = t & 31, cg = t >> 5;
        float acco = 0.f;
#pragma unroll
        for (int cc = 0; cc < 4; ++cc) {
            int c = cg*4 + cc;
            float h = bdw[c];
#pragma unroll
            for (int tt = 0; tt < 6; ++tt) {
                int lp = 4*j + tt - 1;
                float val = (lp < 0) ? hl[0][c] : (lp >= 128 ? hl[1][c] : Os[lp*69 + c]);
                h += Wdw[c*6 + tt] * val;
            }
            float ge = 0.5f * h * (1.0f + erff(h * 0.70710678118654752f));  // exact gelu
            acco += Wp[c] * ge;
        }
        part[cg][j] = acco;
    }
    __syncthreads();
    if (t < 32) {
        float off = 0.f;
#pragma unroll
        for (int cg2 = 0; cg2 < 16; ++cg2) off += part[cg2][t];
        off = tanhf(off) * 4.0f;
        int jg = j0 + t;
        float vg  = 2.0f * ((float)jg + off) / (float)(m - 1) - 1.0f;
        float pos = ((vg + 1.0f) * (float)n - 1.0f) * 0.5f;
        float x0  = floorf(pos);
        x0s[t] = (int)x0;
        w1s[t] = pos - x0;
    }
    __syncthreads();

    // grid-sample gather, both streams: wave w handles j = w*4 + jj
    {
        float a0[4], a1[4], b0[4], b1[4], wg[4];
#pragma unroll
        for (int jj = 0; jj < 4; ++jj) {
            int j = w*4 + jj;
            int ii = x0s[j];
            wg[jj] = w1s[j];
            bool v0 = (ii   >= 0 && ii   < n);
            bool v1 = (ii+1 >= 0 && ii+1 < n);
            a0[jj] = v0 ? px[(size_t)ii*DIMC + g*64 + lane]     : 0.f;
            a1[jj] = v1 ? px[(size_t)(ii+1)*DIMC + g*64 + lane] : 0.f;
            b0[jj] = v0 ? x[(size_t)ii*DIMC + g*64 + lane]      : 0.f;
            b1[jj] = v1 ? x[(size_t)(ii+1)*DIMC + g*64 + lane]  : 0.f;
        }
#pragma unroll
        for (int jj = 0; jj < 4; ++jj) {
            int j = w*4 + jj;
            kvs[0][j*72 + lane] = (_Float16)(a0[jj]*(1.0f - wg[jj]) + a1[jj]*wg[jj]);
            kvs[1][j*72 + lane] = (_Float16)(b0[jj]*(1.0f - wg[jj]) + b1[jj]*wg[jj]);
        }
    }
    __syncthreads();

    // k/v convs: wave (ws = stream, wo = oc-strip); 32 m-rows as 2 row-tiles of 16
    {
        int ws = w >> 2, wo = w & 3;
        half8 bk[2], bv[2];
#pragma unroll
        for (int ks = 0; ks < 2; ++ks) {
            bk[ks] = frag_f32(&Wk[(size_t)(g*64 + wo*16 + l15)*64 + ks*32 + quad*8]);
            bv[ks] = frag_f32(&Wv[(size_t)(g*64 + wo*16 + l15)*64 + ks*32 + quad*8]);
        }
        half8 afk[2][2];
#pragma unroll
        for (int mt = 0; mt < 2; ++mt)
#pragma unroll
            for (int ks = 0; ks < 2; ++ks)
                afk[mt][ks] = *(const half8*)&kvs[ws][(mt*16 + l15)*72 + ks*32 + quad*8];
        f32x4 ack[2], acv[2];
#pragma unroll
        for (int mt = 0; mt < 2; ++mt) { ack[mt] = (f32x4){0.f,0.f,0.f,0.f}; acv[mt] = (f32x4){0.f,0.f,0.f,0.f}; }
#pragma unroll
        for (int ks = 0; ks < 2; ++ks)
#pragma unroll
            for (int mt = 0; mt < 2; ++mt) {
                ack[mt] = __builtin_amdgcn_mfma_f32_16x16x32_f16(afk[mt][ks], bk[ks], ack[mt], 0, 0, 0);
                acv[mt] = __builtin_amdgcn_mfma_f32_16x16x32_f16(afk[mt][ks], bv[ks], acv[mt], 0, 0, 0);
            }
        size_t hb = (size_t)(ws*8 + g);
#pragma unroll
        for (int mt = 0; mt < 2; ++mt) {
#pragma unroll
            for (int r = 0; r < 4; ++r)
                kt16[(hb*m + j0 + mt*16 + quad*4 + r)*64 + wo*16 + l15] = (_Float16)ack[mt][r];
            union { fp16x2 h2[2]; uint2 v; } pv;
            pv.h2[0] = __builtin_amdgcn_cvt_pkrtz(acv[mt][0], acv[mt][1]);
            pv.h2[1] = __builtin_amdgcn_cvt_pkrtz(acv[mt][2], acv[mt][3]);
            *(uint2*)&vt16[(hb*64 + wo*16 + l15)*m + j0 + mt*16 + quad*4] = pv.v;   // 4 consecutive j
        }
    }
}

// ---------------- flash attention v8 (round-9 winner): 512 threads, 256 q-rows ----------------
// 8 waves share one K/V staging: 1 load + 1 commit per thread per array per tile;
// K/V L2 re-reads halve; each barrier amortizes 32 rows/wave of MFMA. LDS 73 KB.
__global__ __launch_bounds__(512, 1) void k_attn(
    const _Float16* __restrict__ qh, const _Float16* __restrict__ kt16,
    const _Float16* __restrict__ vt16, _Float16* __restrict__ aoh, int n, int m)
{
    __shared__ _Float16 Ks[2][64*72]; // K tile [j][d], row stride 72
    __shared__ _Float16 Vs[2][64*72]; // V tile [d][j], row stride 72
    __shared__ _Float16 Ps[256*72];   // P^T strips; reused as O transpose buffer in epilogue
    int nit = n >> 8;                 // 256 q-rows per block
    int it = blockIdx.x % nit;
    int h  = (blockIdx.x / nit) & 7;
    int s  = blockIdx.x / (nit*8);
    int t  = threadIdx.x;
    int lane = t & 63, w = t >> 6;    // w in 0..7
    int l15 = lane & 15, quad = lane >> 4;
    int i0 = it*256;

    // Q B-frags: wave w owns i-strip [i0 + w*32, +32)
    const _Float16* qb = &qh[((size_t)h*n + i0)*64];
    half8 bqv[2][2];
#pragma unroll
    for (int ks = 0; ks < 2; ++ks)
#pragma unroll
        for (int i2 = 0; i2 < 2; ++i2)
            bqv[ks][i2] = *(const half8*)&qb[(w*32 + i2*16 + l15)*64 + ks*32 + quad*8];

    const _Float16* kb = &kt16[(size_t)(s*8+h)*m*64];   // [j][d]
    const _Float16* vb = &vt16[(size_t)(s*8+h)*64*m];   // [d][j]

    int r0 = t >> 3, oct = t & 7;     // r0 in 0..63: one row per thread

    float lsum[2] = {0.f, 0.f};
    f32x4 oaccT[4][2];
#pragma unroll
    for (int dt = 0; dt < 4; ++dt)
#pragma unroll
        for (int i2 = 0; i2 < 2; ++i2) oaccT[dt][i2] = (f32x4){0.f,0.f,0.f,0.f};

    // prefetch + commit K/V tile 0 into buf 0 (coalesced; one row per thread)
    uint4 pv0 = *(const uint4*)&vb[(size_t)r0*m + oct*8];
    uint4 pk0 = *(const uint4*)&kb[(size_t)r0*64 + oct*8];
    *(uint4*)&Vs[0][r0*72 + oct*8] = pv0;
    *(uint4*)&Ks[0][r0*72 + oct*8] = pk0;

    int ntile = m >> 6;
    for (int tk = 0; tk < ntile; ++tk) {
        bool pf = (tk + 1 < ntile);
        if (pf) {   // next K/V tiles' global loads, latency hidden by compute
            pv0 = *(const uint4*)&vb[(size_t)r0*m + (tk+1)*64 + oct*8];
            pk0 = *(const uint4*)&kb[(size_t)((tk+1)*64 + r0)*64 + oct*8];
        }

        __syncthreads();   // K/V buf[tk&1] committed; prior tile's reads done
        const _Float16* KB = Ks[tk & 1];
        const _Float16* VB = Vs[tk & 1];
        half8 aqv[2][4];
#pragma unroll
        for (int ks = 0; ks < 2; ++ks)
#pragma unroll
            for (int jt = 0; jt < 4; ++jt)
                aqv[ks][jt] = *(const half8*)&KB[(jt*16 + l15)*72 + ks*32 + quad*8];
        half8 avv[2][4];
#pragma unroll
        for (int ks = 0; ks < 2; ++ks)
#pragma unroll
            for (int dt = 0; dt < 4; ++dt)
                avv[ks][dt] = *(const half8*)&VB[(dt*16 + l15)*72 + ks*32 + quad*8];

        // --- S^T = K Q^T over wave's 32-i strip ---
        f32x4 accs[4][2];
#pragma unroll
        for (int jt = 0; jt < 4; ++jt)
#pragma unroll
            for (int i2 = 0; i2 < 2; ++i2) accs[jt][i2] = (f32x4){0.f,0.f,0.f,0.f};
        __builtin_amdgcn_s_setprio(1);
#pragma unroll
        for (int ks = 0; ks < 2; ++ks)
#pragma unroll
            for (int jt = 0; jt < 4; ++jt)
#pragma unroll
                for (int i2 = 0; i2 < 2; ++i2)
                    accs[jt][i2] = __builtin_amdgcn_mfma_f32_16x16x32_f16(
                        aqv[ks][jt], bqv[ks][i2], accs[jt][i2], 0, 0, 0);
        __builtin_amdgcn_s_setprio(0);

        // --- p = exp2(t - MSHIFT); partial row sums; pack + vectored P^T write (wave-private) ---
#pragma unroll
        for (int jt = 0; jt < 4; ++jt)
#pragma unroll
            for (int i2 = 0; i2 < 2; ++i2) {
                f32x4 p;
#pragma unroll
                for (int r = 0; r < 4; ++r) p[r] = __builtin_amdgcn_exp2f(accs[jt][i2][r] - MSHIFT);
                lsum[i2] += (p[0]+p[1]) + (p[2]+p[3]);
                union { fp16x2 h; int i; } c0, c1;
                c0.h = __builtin_amdgcn_cvt_pkrtz(p[0], p[1]);
                c1.h = __builtin_amdgcn_cvt_pkrtz(p[2], p[3]);
                *(int2*)&Ps[(w*32 + i2*16 + l15)*72 + jt*16 + quad*4] = make_int2(c0.i, c1.i);
            }

        // --- O^T += V^T P^T ---
        __builtin_amdgcn_s_setprio(1);
#pragma unroll
        for (int ks = 0; ks < 2; ++ks)
#pragma unroll
            for (int i2 = 0; i2 < 2; ++i2) {
                half8 bp = *(const half8*)&Ps[(w*32 + i2*16 + l15)*72 + ks*32 + quad*8];
#pragma unroll
                for (int dt = 0; dt < 4; ++dt)
                    oaccT[dt][i2] = __builtin_amdgcn_mfma_f32_16x16x32_f16(
                        avv[ks][dt], bp, oaccT[dt][i2], 0, 0, 0);
            }
        __builtin_amdgcn_s_setprio(0);

        if (pf) {   // commit next K/V tiles into the other buffer
            int b2 = (tk + 1) & 1;
            *(uint4*)&Vs[b2][r0*72 + oct*8] = pv0;
            *(uint4*)&Ks[b2][r0*72 + oct*8] = pk0;
        }
    }

    // --- finalize ---
#pragma unroll
    for (int i2 = 0; i2 < 2; ++i2) {
        lsum[i2] += __shfl_xor(lsum[i2], 16, 64);
        lsum[i2] += __shfl_xor(lsum[i2], 32, 64);
    }
    float inv[2] = {1.0f / lsum[0], 1.0f / lsum[1]};
#pragma unroll
    for (int dt = 0; dt < 4; ++dt)
#pragma unroll
        for (int i2 = 0; i2 < 2; ++i2)
#pragma unroll
            for (int r = 0; r < 4; ++r)
                Ps[(w*32 + i2*16 + l15)*72 + dt*16 + quad*4 + r]
                    = (_Float16)(oaccT[dt][i2][r] * inv[i2]);
    {
        int row = w*32 + (lane >> 1);                // 0..255
        int dbase = (lane & 1) * 32;
        int pbase = s*64 + h*8 + (dbase >> 3);       // panel index of c' = s*512+h*64+dbase
        size_t APs = (size_t)n * 8;                  // f16 per panel
#pragma unroll
        for (int k2 = 0; k2 < 4; ++k2) {
            uint4 v = *(uint4*)&Ps[row*72 + dbase + k2*8];
            *(uint4*)&aoh[(size_t)(pbase + k2)*APs + (size_t)(i0 + row)*8] = v;
        }
    }
}

// ---------------- Wo GEMM, f16 MFMA, zero-LDS, PANEL-layout operands ----------------
// aoh and Woh are stored as [K-panel][row][8] -> every A/B fragment load is 16 lanes
// x contiguous 16B (2 cache lines) instead of a 16-line scatter. Linearity fold:
// out = bias + 0.5*(O_s0 + O_s1)·Wo — panels p and p+64 share the same Wo panel.
__global__ __launch_bounds__(256) void k_out(
    const _Float16* __restrict__ aoh, const _Float16* __restrict__ Woh,
    const float* __restrict__ bo, float* __restrict__ out, int n)
{
    int i0 = blockIdx.x*64, d0 = blockIdx.y*64;
    int t = threadIdx.x;
    int lane = t & 63, w = t >> 6;
    int l15 = lane & 15, quad = lane >> 4;
    f32x4 oacc[4];
#pragma unroll
    for (int dt = 0; dt < 4; ++dt) oacc[dt] = (f32x4){0.f,0.f,0.f,0.f};

    size_t APs = (size_t)n * 8;
    int arow = (i0 + w*16 + l15) * 8;
#pragma unroll 4
    for (int ks = 0; ks < 16; ++ks) {            // K' = 1024 folded to 512 via stream pre-sum
        int p = ks*4 + quad;                     // A/B panel for this (ks, quad)
        half8 aq0 = *(const half8*)&aoh[(size_t)p*APs + arow];
        half8 aq1 = *(const half8*)&aoh[(size_t)(p + 64)*APs + arow];
        half8 aqs = aq0 + aq1;                   // packed f16 add; 0.5 applied at epilogue
#pragma unroll
        for (int dt = 0; dt < 4; ++dt) {
            half8 bw = *(const half8*)&Woh[(size_t)p*4096 + (d0 + dt*16 + l15)*8];
            oacc[dt] = __builtin_amdgcn_mfma_f32_16x16x32_f16(aqs, bw, oacc[dt], 0, 0, 0);
        }
    }
#pragma unroll
    for (int dt = 0; dt < 4; ++dt) {
        float bias = bo[d0 + dt*16 + l15];
#pragma unroll
        for (int r = 0; r < 4; ++r)
            out[(size_t)(i0 + w*16 + quad*4 + r)*DIMC + d0 + dt*16 + l15]
                = bias + 0.5f*oacc[dt][r];
    }
}

extern "C" void kernel_launch(void* const* d_in, const int* in_sizes, int n_in,
                              void* d_out, int out_size, void* d_ws, size_t ws_size,
                              hipStream_t stream)
{
    const float* x   = (const float*)d_in[0];
    const float* px  = (const float*)d_in[1];
    const float* Wq  = (const float*)d_in[2];
    const float* Wk  = (const float*)d_in[3];
    const float* Wv  = (const float*)d_in[4];
    const float* Wo  = (const float*)d_in[5];
    const float* bo  = (const float*)d_in[6];
    const float* Wdw = (const float*)d_in[7];
    const float* bdw = (const float*)d_in[8];
    const float* Wp  = (const float*)d_in[9];
    float* out = (float*)d_out;
    int n = in_sizes[0] / DIMC;     // 4096
    int m = n / 4;                  // 1024

    _Float16* qhf  = (_Float16*)d_ws;                 // 8*n*64 f16   [h][i][d]
    _Float16* kt16 = qhf + (size_t)8*n*64;            // 2*8*m*64 f16 [s][h][j][d]
    _Float16* vt16 = kt16 + (size_t)16*m*64;          // 2*8*m*64 f16 [s][h][d][j]
    _Float16* aoh  = vt16 + (size_t)16*m*64;          // n*1024 f16   PANEL [c'/8][i][8]
    _Float16* Woh  = aoh + (size_t)n*1024;            // 512*512 f16  PANEL [c/8][d][8]

    k_front<<<8*(m/32),    512, 0, stream>>>(x, px, Wq, Wk, Wv, Wo, Wdw, bdw, Wp,
                                             qhf, kt16, vt16, Woh, n, m);
    k_attn <<<2*8*(n/256), 512, 0, stream>>>(qhf, kt16, vt16, aoh, n, m);
    k_out  <<<dim3(n/64, 8), 256, 0, stream>>>(aoh, Woh, bo, out, n);
}

// Round 12
// 126.132 us; speedup vs baseline: 1.0482x; 1.0189x over previous
//
#include <hip/hip_runtime.h>
#include <math.h>

#define DIMC 512
#define NG 8
// q pre-scale: 64^-0.5 * log2(e)  (so scores come out in exp2 units)
#define QSCALE 0.18033688011112042f
// softmax fixed shift: 5 * log2(e)
#define MSHIFT 7.2134752044448170f

typedef _Float16 half8 __attribute__((ext_vector_type(8)));
typedef __fp16 fp16x2 __attribute__((ext_vector_type(2)));
typedef float f32x4 __attribute__((ext_vector_type(4)));

// build a half8 MFMA fragment from 8 consecutive global f32
__device__ __forceinline__ half8 frag_f32(const float* p) {
    float4 a = *(const float4*)p;
    float4 b = *(const float4*)(p + 4);
    union { fp16x2 h2[4]; half8 h8; } u;
    u.h2[0] = __builtin_amdgcn_cvt_pkrtz(a.x, a.y);
    u.h2[1] = __builtin_amdgcn_cvt_pkrtz(a.z, a.w);
    u.h2[2] = __builtin_amdgcn_cvt_pkrtz(b.x, b.y);
    u.h2[3] = __builtin_amdgcn_cvt_pkrtz(b.z, b.w);
    return u.h8;
}

// ---------------- fused front-end v2: de-scattered (round-9 best config) ----------------
// 64 q-positions / 16 m-positions per block -> 512 blocks -> 2 blocks/CU.
// (v3's 512-thread/1-block-per-CU variant measured +0.7: single barrier domain loses
//  the cross-block overlap that pays for the halved fixed costs — same rule as attn v9.)
// Staging dense/coalesced (f32->f16, stride-136 rows); frags via ds_read_b128;
// halo folded into a 2-row zero-padded MFMA on wave 0.
// Also: first 128 blocks cast Wo f32->f16 in K-PANEL layout [c/8][d][8].
__global__ __launch_bounds__(256, 2) void k_front(
    const float* __restrict__ x, const float* __restrict__ px,
    const float* __restrict__ Wq, const float* __restrict__ Wk,
    const float* __restrict__ Wv, const float* __restrict__ Wo,
    const float* __restrict__ Wdw, const float* __restrict__ bdw,
    const float* __restrict__ Wp, _Float16* __restrict__ qh,
    _Float16* __restrict__ kt16, _Float16* __restrict__ vt16,
    _Float16* __restrict__ Woh, int n, int m)
{
    __shared__ float Os[64*69];        // [i][oc] q tile, stride 69
    __shared__ float hl[2][64];        // halo q: [side][c]
    __shared__ float part[16][16];
    __shared__ int   x0s[16];
    __shared__ float w1s[16];
    __shared__ _Float16 kvs[2][16*72]; // gathered kv, per stream
    __shared__ _Float16 SRCs[64*136];  // staged SRC slice [i][c], f16
    __shared__ _Float16 Wqs[64*136];   // staged Wq slice [oc][c], f16
    int g  = blockIdx.x & 7;
    int jt = blockIdx.x >> 3;
    int P0 = jt*64, j0 = jt*16;
    int t  = threadIdx.x;
    int lane = t & 63, w = t >> 6;
    int l15 = lane & 15, quad = lane >> 4;
    const float* SRC = (g < 4) ? px : x;    // concat puts prev first
    int cbase = (g & 3) * 128;

    // Wo cast -> PANEL layout Woh[(c>>3)][d][8] (first 128 blocks, 2048 elems each)
    if (blockIdx.x < 128) {
        int idx = blockIdx.x*2048 + t*8;
        int d = idx >> 9, c0 = idx & 511;       // 8 consecutive c in one panel
        float4 a = *(const float4*)&Wo[idx];
        float4 b = *(const float4*)&Wo[idx+4];
        union { fp16x2 h2[4]; uint4 v; } pk;
        pk.h2[0] = __builtin_amdgcn_cvt_pkrtz(a.x, a.y);
        pk.h2[1] = __builtin_amdgcn_cvt_pkrtz(a.z, a.w);
        pk.h2[2] = __builtin_amdgcn_cvt_pkrtz(b.x, b.y);
        pk.h2[3] = __builtin_amdgcn_cvt_pkrtz(b.z, b.w);
        *(uint4*)&Woh[(c0>>3)*4096 + d*8] = pk.v;
    }

    // ---- stage SRC + Wq slices into LDS (dense coalesced, f32->f16) ----
    {
        int r = t >> 2, c0 = (t & 3) * 32;
        const float* sp = &SRC[(size_t)(P0 + r)*DIMC + cbase + c0];
        const float* wp = &Wq[(size_t)(g*64 + r)*128 + c0];
#pragma unroll
        for (int u = 0; u < 4; ++u) {
            *(half8*)&SRCs[r*136 + c0 + u*8] = frag_f32(sp + u*8);
            *(half8*)&Wqs [r*136 + c0 + u*8] = frag_f32(wp + u*8);
        }
    }

    // halo A-frags (wave 0): rows P0-1 (l15==0) and P0+64 (l15==1), zero-padded
    half8 afh[4];
    if (w == 0) {
        int p = (l15 == 0) ? (P0 - 1) : (P0 + 64);
        bool hv = (l15 < 2) && (p >= 0) && (p < n);
        half8 z;
#pragma unroll
        for (int u = 0; u < 8; ++u) z[u] = (_Float16)0.f;
#pragma unroll
        for (int ks = 0; ks < 4; ++ks)
            afh[ks] = hv ? frag_f32(&SRC[(size_t)p*DIMC + cbase + ks*32 + quad*8]) : z;
    }
    __syncthreads();

    // main q tile via f16 MFMA: wave w owns i-strip [P0+w*16, +16); frags from LDS
    half8 af[4];
#pragma unroll
    for (int ks = 0; ks < 4; ++ks)
        af[ks] = *(const half8*)&SRCs[(w*16 + l15)*136 + ks*32 + quad*8];
    f32x4 acc[4], acch[4];
#pragma unroll
    for (int nt = 0; nt < 4; ++nt) { acc[nt] = (f32x4){0.f,0.f,0.f,0.f}; acch[nt] = (f32x4){0.f,0.f,0.f,0.f}; }
#pragma unroll
    for (int ks = 0; ks < 4; ++ks)
#pragma unroll
        for (int nt = 0; nt < 4; ++nt) {
            half8 bf = *(const half8*)&Wqs[(nt*16 + l15)*136 + ks*32 + quad*8];
            acc[nt] = __builtin_amdgcn_mfma_f32_16x16x32_f16(af[ks], bf, acc[nt], 0, 0, 0);
            if (w == 0)
                acch[nt] = __builtin_amdgcn_mfma_f32_16x16x32_f16(afh[ks], bf, acch[nt], 0, 0, 0);
        }
    // C-layout -> Os[i][oc]; halo rows 0,1 of acch -> hl[side][oc]
#pragma unroll
    for (int nt = 0; nt < 4; ++nt)
#pragma unroll
        for (int r = 0; r < 4; ++r)
            Os[(w*16 + quad*4 + r)*69 + nt*16 + l15] = acc[nt][r];
    if (w == 0 && quad == 0)
#pragma unroll
        for (int nt = 0; nt < 4; ++nt) {
            hl[0][nt*16 + l15] = acch[nt][0];
            hl[1][nt*16 + l15] = acch[nt][1];
        }
    __syncthreads();

    // qh f16 [h][i][d] with QSCALE: thread covers a quarter row (16 f16)
    {
        int i = t >> 2, hf = t & 3;
        union { _Float16 h[16]; uint4 v[2]; } pk;
#pragma unroll
        for (int u = 0; u < 16; ++u) pk.h[u] = (_Float16)(Os[i*69 + hf*16 + u] * QSCALE);
        uint4* dst = (uint4*)&qh[((size_t)g*n + P0 + i)*64 + hf*16];
        dst[0] = pk.v[0]; dst[1] = pk.v[1];
    }

    // offset net straight from LDS: thread = (j = t&15, cg = t>>4, 4 channels each)
    {
        int j = t & 15, cg = t >> 4;
        float acco = 0.f;
#pragma unroll
        for (int cc = 0; cc < 4; ++cc) {
            int c = cg*4 + cc;
            float h = bdw[c];
#pragma unroll
            for (int tt = 0; tt < 6; ++tt) {
                int lp = 4*j + tt - 1;
                float val = (lp < 0) ? hl[0][c] : (lp >= 64 ? hl[1][c] : Os[lp*69 + c]);
                h += Wdw[c*6 + tt] * val;
            }
            float ge = 0.5f * h * (1.0f + erff(h * 0.70710678118654752f));  // exact gelu
            acco += Wp[c] * ge;
        }
        part[cg][j] = acco;
    }
    __syncthreads();
    if (t < 16) {
        float off = 0.f;
#pragma unroll
        for (int cg2 = 0; cg2 < 16; ++cg2) off += part[cg2][t];
        off = tanhf(off) * 4.0f;
        int jg = j0 + t;
        float vg  = 2.0f * ((float)jg + off) / (float)(m - 1) - 1.0f;
        float pos = ((vg + 1.0f) * (float)n - 1.0f) * 0.5f;
        float x0  = floorf(pos);
        x0s[t] = (int)x0;
        w1s[t] = pos - x0;
    }
    __syncthreads();

    // grid-sample gather, both streams (prefetch loads, then lerp+commit)
    {
        float a0[4], a1[4], b0[4], b1[4], wg[4];
#pragma unroll
        for (int jj = 0; jj < 4; ++jj) {
            int j = jj*4 + w;
            int ii = x0s[j];
            wg[jj] = w1s[j];
            bool v0 = (ii   >= 0 && ii   < n);
            bool v1 = (ii+1 >= 0 && ii+1 < n);
            a0[jj] = v0 ? px[(size_t)ii*DIMC + g*64 + lane]     : 0.f;
            a1[jj] = v1 ? px[(size_t)(ii+1)*DIMC + g*64 + lane] : 0.f;
            b0[jj] = v0 ? x[(size_t)ii*DIMC + g*64 + lane]      : 0.f;
            b1[jj] = v1 ? x[(size_t)(ii+1)*DIMC + g*64 + lane]  : 0.f;
        }
#pragma unroll
        for (int jj = 0; jj < 4; ++jj) {
            kvs[0][(jj*4 + w)*72 + lane] = (_Float16)(a0[jj]*(1.0f - wg[jj]) + a1[jj]*wg[jj]);
            kvs[1][(jj*4 + w)*72 + lane] = (_Float16)(b0[jj]*(1.0f - wg[jj]) + b1[jj]*wg[jj]);
        }
    }
    __syncthreads();

    // k/v convs: B-frags from global (shared across streams); wave w owns oc-strip w*16
    half8 bk[2], bv[2];
#pragma unroll
    for (int ks = 0; ks < 2; ++ks) {
        bk[ks] = frag_f32(&Wk[(size_t)(g*64 + w*16 + l15)*64 + ks*32 + quad*8]);
        bv[ks] = frag_f32(&Wv[(size_t)(g*64 + w*16 + l15)*64 + ks*32 + quad*8]);
    }
#pragma unroll
    for (int s = 0; s < 2; ++s) {
        half8 afk[2];
#pragma unroll
        for (int ks = 0; ks < 2; ++ks)
            afk[ks] = *(const half8*)&kvs[s][l15*72 + ks*32 + quad*8];
        f32x4 ack = (f32x4){0.f,0.f,0.f,0.f};
        f32x4 acv = (f32x4){0.f,0.f,0.f,0.f};
#pragma unroll
        for (int ks = 0; ks < 2; ++ks) {
            ack = __builtin_amdgcn_mfma_f32_16x16x32_f16(afk[ks], bk[ks], ack, 0, 0, 0);
            acv = __builtin_amdgcn_mfma_f32_16x16x32_f16(afk[ks], bv[ks], acv, 0, 0, 0);
        }
        size_t hb = (size_t)(s*8 + g);
#pragma unroll
        for (int r = 0; r < 4; ++r)
            kt16[(hb*m + j0 + quad*4 + r)*64 + w*16 + l15] = (_Float16)ack[r];
        union { fp16x2 h2[2]; uint2 v; } pv;
        pv.h2[0] = __builtin_amdgcn_cvt_pkrtz(acv[0], acv[1]);
        pv.h2[1] = __builtin_amdgcn_cvt_pkrtz(acv[2], acv[3]);
        *(uint2*)&vt16[(hb*64 + w*16 + l15)*m + j0 + quad*4] = pv.v;   // 4 consecutive j
    }
}

// ---------------- flash attention v8 (round-9 winner): 512 threads, 256 q-rows ----------------
// 8 waves share one K/V staging: 1 load + 1 commit per thread per array per tile;
// K/V L2 re-reads halve; each barrier amortizes 32 rows/wave of MFMA. LDS 73 KB.
__global__ __launch_bounds__(512, 1) void k_attn(
    const _Float16* __restrict__ qh, const _Float16* __restrict__ kt16,
    const _Float16* __restrict__ vt16, _Float16* __restrict__ aoh, int n, int m)
{
    __shared__ _Float16 Ks[2][64*72]; // K tile [j][d], row stride 72
    __shared__ _Float16 Vs[2][64*72]; // V tile [d][j], row stride 72
    __shared__ _Float16 Ps[256*72];   // P^T strips; reused as O transpose buffer in epilogue
    int nit = n >> 8;                 // 256 q-rows per block
    int it = blockIdx.x % nit;
    int h  = (blockIdx.x / nit) & 7;
    int s  = blockIdx.x / (nit*8);
    int t  = threadIdx.x;
    int lane = t & 63, w = t >> 6;    // w in 0..7
    int l15 = lane & 15, quad = lane >> 4;
    int i0 = it*256;

    // Q B-frags: wave w owns i-strip [i0 + w*32, +32)
    const _Float16* qb = &qh[((size_t)h*n + i0)*64];
    half8 bqv[2][2];
#pragma unroll
    for (int ks = 0; ks < 2; ++ks)
#pragma unroll
        for (int i2 = 0; i2 < 2; ++i2)
            bqv[ks][i2] = *(const half8*)&qb[(w*32 + i2*16 + l15)*64 + ks*32 + quad*8];

    const _Float16* kb = &kt16[(size_t)(s*8+h)*m*64];   // [j][d]
    const _Float16* vb = &vt16[(size_t)(s*8+h)*64*m];   // [d][j]

    int r0 = t >> 3, oct = t & 7;     // r0 in 0..63: one row per thread

    float lsum[2] = {0.f, 0.f};
    f32x4 oaccT[4][2];
#pragma unroll
    for (int dt = 0; dt < 4; ++dt)
#pragma unroll
        for (int i2 = 0; i2 < 2; ++i2) oaccT[dt][i2] = (f32x4){0.f,0.f,0.f,0.f};

    // prefetch + commit K/V tile 0 into buf 0 (coalesced; one row per thread)
    uint4 pv0 = *(const uint4*)&vb[(size_t)r0*m + oct*8];
    uint4 pk0 = *(const uint4*)&kb[(size_t)r0*64 + oct*8];
    *(uint4*)&Vs[0][r0*72 + oct*8] = pv0;
    *(uint4*)&Ks[0][r0*72 + oct*8] = pk0;

    int ntile = m >> 6;
    for (int tk = 0; tk < ntile; ++tk) {
        bool pf = (tk + 1 < ntile);
        if (pf) {   // next K/V tiles' global loads, latency hidden by compute
            pv0 = *(const uint4*)&vb[(size_t)r0*m + (tk+1)*64 + oct*8];
            pk0 = *(const uint4*)&kb[(size_t)((tk+1)*64 + r0)*64 + oct*8];
        }

        __syncthreads();   // K/V buf[tk&1] committed; prior tile's reads done
        const _Float16* KB = Ks[tk & 1];
        const _Float16* VB = Vs[tk & 1];
        half8 aqv[2][4];
#pragma unroll
        for (int ks = 0; ks < 2; ++ks)
#pragma unroll
            for (int jt = 0; jt < 4; ++jt)
                aqv[ks][jt] = *(const half8*)&KB[(jt*16 + l15)*72 + ks*32 + quad*8];
        half8 avv[2][4];
#pragma unroll
        for (int ks = 0; ks < 2; ++ks)
#pragma unroll
            for (int dt = 0; dt < 4; ++dt)
                avv[ks][dt] = *(const half8*)&VB[(dt*16 + l15)*72 + ks*32 + quad*8];

        // --- S^T = K Q^T over wave's 32-i strip ---
        f32x4 accs[4][2];
#pragma unroll
        for (int jt = 0; jt < 4; ++jt)
#pragma unroll
            for (int i2 = 0; i2 < 2; ++i2) accs[jt][i2] = (f32x4){0.f,0.f,0.f,0.f};
        __builtin_amdgcn_s_setprio(1);
#pragma unroll
        for (int ks = 0; ks < 2; ++ks)
#pragma unroll
            for (int jt = 0; jt < 4; ++jt)
#pragma unroll
                for (int i2 = 0; i2 < 2; ++i2)
                    accs[jt][i2] = __builtin_amdgcn_mfma_f32_16x16x32_f16(
                        aqv[ks][jt], bqv[ks][i2], accs[jt][i2], 0, 0, 0);
        __builtin_amdgcn_s_setprio(0);

        // --- p = exp2(t - MSHIFT); partial row sums; pack + vectored P^T write (wave-private) ---
#pragma unroll
        for (int jt = 0; jt < 4; ++jt)
#pragma unroll
            for (int i2 = 0; i2 < 2; ++i2) {
                f32x4 p;
#pragma unroll
                for (int r = 0; r < 4; ++r) p[r] = __builtin_amdgcn_exp2f(accs[jt][i2][r] - MSHIFT);
                lsum[i2] += (p[0]+p[1]) + (p[2]+p[3]);
                union { fp16x2 h; int i; } c0, c1;
                c0.h = __builtin_amdgcn_cvt_pkrtz(p[0], p[1]);
                c1.h = __builtin_amdgcn_cvt_pkrtz(p[2], p[3]);
                *(int2*)&Ps[(w*32 + i2*16 + l15)*72 + jt*16 + quad*4] = make_int2(c0.i, c1.i);
            }

        // --- O^T += V^T P^T ---
        __builtin_amdgcn_s_setprio(1);
#pragma unroll
        for (int ks = 0; ks < 2; ++ks)
#pragma unroll
            for (int i2 = 0; i2 < 2; ++i2) {
                half8 bp = *(const half8*)&Ps[(w*32 + i2*16 + l15)*72 + ks*32 + quad*8];
#pragma unroll
                for (int dt = 0; dt < 4; ++dt)
                    oaccT[dt][i2] = __builtin_amdgcn_mfma_f32_16x16x32_f16(
                        avv[ks][dt], bp, oaccT[dt][i2], 0, 0, 0);
            }
        __builtin_amdgcn_s_setprio(0);

        if (pf) {   // commit next K/V tiles into the other buffer
            int b2 = (tk + 1) & 1;
            *(uint4*)&Vs[b2][r0*72 + oct*8] = pv0;
            *(uint4*)&Ks[b2][r0*72 + oct*8] = pk0;
        }
    }

    // --- finalize ---
#pragma unroll
    for (int i2 = 0; i2 < 2; ++i2) {
        lsum[i2] += __shfl_xor(lsum[i2], 16, 64);
        lsum[i2] += __shfl_xor(lsum[i2], 32, 64);
    }
    float inv[2] = {1.0f / lsum[0], 1.0f / lsum[1]};
#pragma unroll
    for (int dt = 0; dt < 4; ++dt)
#pragma unroll
        for (int i2 = 0; i2 < 2; ++i2)
#pragma unroll
            for (int r = 0; r < 4; ++r)
                Ps[(w*32 + i2*16 + l15)*72 + dt*16 + quad*4 + r]
                    = (_Float16)(oaccT[dt][i2][r] * inv[i2]);
    {
        int row = w*32 + (lane >> 1);                // 0..255
        int dbase = (lane & 1) * 32;
        int pbase = s*64 + h*8 + (dbase >> 3);       // panel index of c' = s*512+h*64+dbase
        size_t APs = (size_t)n * 8;                  // f16 per panel
#pragma unroll
        for (int k2 = 0; k2 < 4; ++k2) {
            uint4 v = *(uint4*)&Ps[row*72 + dbase + k2*8];
            *(uint4*)&aoh[(size_t)(pbase + k2)*APs + (size_t)(i0 + row)*8] = v;
        }
    }
}

// ---------------- Wo GEMM, f16 MFMA, zero-LDS, PANEL-layout operands ----------------
// aoh and Woh are stored as [K-panel][row][8] -> every A/B fragment load is 16 lanes
// x contiguous 16B (2 cache lines) instead of a 16-line scatter. Linearity fold:
// out = bias + 0.5*(O_s0 + O_s1)·Wo — panels p and p+64 share the same Wo panel.
__global__ __launch_bounds__(256) void k_out(
    const _Float16* __restrict__ aoh, const _Float16* __restrict__ Woh,
    const float* __restrict__ bo, float* __restrict__ out, int n)
{
    int i0 = blockIdx.x*64, d0 = blockIdx.y*64;
    int t = threadIdx.x;
    int lane = t & 63, w = t >> 6;
    int l15 = lane & 15, quad = lane >> 4;
    f32x4 oacc[4];
#pragma unroll
    for (int dt = 0; dt < 4; ++dt) oacc[dt] = (f32x4){0.f,0.f,0.f,0.f};

    size_t APs = (size_t)n * 8;
    int arow = (i0 + w*16 + l15) * 8;
#pragma unroll 4
    for (int ks = 0; ks < 16; ++ks) {            // K' = 1024 folded to 512 via stream pre-sum
        int p = ks*4 + quad;                     // A/B panel for this (ks, quad)
        half8 aq0 = *(const half8*)&aoh[(size_t)p*APs + arow];
        half8 aq1 = *(const half8*)&aoh[(size_t)(p + 64)*APs + arow];
        half8 aqs = aq0 + aq1;                   // packed f16 add; 0.5 applied at epilogue
#pragma unroll
        for (int dt = 0; dt < 4; ++dt) {
            half8 bw = *(const half8*)&Woh[(size_t)p*4096 + (d0 + dt*16 + l15)*8];
            oacc[dt] = __builtin_amdgcn_mfma_f32_16x16x32_f16(aqs, bw, oacc[dt], 0, 0, 0);
        }
    }
#pragma unroll
    for (int dt = 0; dt < 4; ++dt) {
        float bias = bo[d0 + dt*16 + l15];
#pragma unroll
        for (int r = 0; r < 4; ++r)
            out[(size_t)(i0 + w*16 + quad*4 + r)*DIMC + d0 + dt*16 + l15]
                = bias + 0.5f*oacc[dt][r];
    }
}

extern "C" void kernel_launch(void* const* d_in, const int* in_sizes, int n_in,
                              void* d_out, int out_size, void* d_ws, size_t ws_size,
                              hipStream_t stream)
{
    const float* x   = (const float*)d_in[0];
    const float* px  = (const float*)d_in[1];
    const float* Wq  = (const float*)d_in[2];
    const float* Wk  = (const float*)d_in[3];
    const float* Wv  = (const float*)d_in[4];
    const float* Wo  = (const float*)d_in[5];
    const float* bo  = (const float*)d_in[6];
    const float* Wdw = (const float*)d_in[7];
    const float* bdw = (const float*)d_in[8];
    const float* Wp  = (const float*)d_in[9];
    float* out = (float*)d_out;
    int n = in_sizes[0] / DIMC;     // 4096
    int m = n / 4;                  // 1024

    _Float16* qhf  = (_Float16*)d_ws;                 // 8*n*64 f16   [h][i][d]
    _Float16* kt16 = qhf + (size_t)8*n*64;            // 2*8*m*64 f16 [s][h][j][d]
    _Float16* vt16 = kt16 + (size_t)16*m*64;          // 2*8*m*64 f16 [s][h][d][j]
    _Float16* aoh  = vt16 + (size_t)16*m*64;          // n*1024 f16   PANEL [c'/8][i][8]
    _Float16* Woh  = aoh + (size_t)n*1024;            // 512*512 f16  PANEL [c/8][d][8]

    k_front<<<8*(m/16),    256, 0, stream>>>(x, px, Wq, Wk, Wv, Wo, Wdw, bdw, Wp,
                                             qhf, kt16, vt16, Woh, n, m);
    k_attn <<<2*8*(n/256), 512, 0, stream>>>(qhf, kt16, vt16, aoh, n, m);
    k_out  <<<dim3(n/64, 8), 256, 0, stream>>>(aoh, Woh, bo, out, n);
}